// Round 9
// baseline (179.308 us; speedup 1.0000x reference)
//
#include <hip/hip_runtime.h>
#include <hip/hip_bf16.h>

typedef __attribute__((ext_vector_type(8))) short short8;
typedef __attribute__((ext_vector_type(4))) float f32x4;

#define NPROTO 64
#define DIM    512
#define TAU_INV 5.0f

__device__ __forceinline__ unsigned short f2bf(float f) {
    union { float f; unsigned int u; } v; v.f = f;
    unsigned int r = v.u + 0x7FFFu + ((v.u >> 16) & 1u);  // round-to-nearest-even
    return (unsigned short)(r >> 16);
}

// ---------------------------------------------------------------------------
// Prep: p_norm (normalized protos, bf16, [64][512]) and protos^T (raw, bf16,
// [512][64]).
// ---------------------------------------------------------------------------
__global__ void pb_prep(const float* __restrict__ protos,
                        unsigned short* __restrict__ pnorm,
                        unsigned short* __restrict__ protosT) {
    const int k    = blockIdx.x;
    const int lane = threadIdx.x;
    const float* row = protos + k * DIM;
    float x[8];
    float ss = 0.0f;
#pragma unroll
    for (int j = 0; j < 8; ++j) {
        x[j] = row[lane * 8 + j];
        ss += x[j] * x[j];
    }
#pragma unroll
    for (int m = 1; m < 64; m <<= 1) ss += __shfl_xor(ss, m, 64);
    const float s = 1.0f / fmaxf(sqrtf(ss), 1e-12f);
    short8 pn;
#pragma unroll
    for (int j = 0; j < 8; ++j) pn[j] = (short)f2bf(x[j] * s);
    *reinterpret_cast<short8*>(pnorm + k * DIM + lane * 8) = pn;
#pragma unroll
    for (int j = 0; j < 8; ++j)
        protosT[(lane * 8 + j) * NPROTO + k] = f2bf(x[j]);
}

// ---------------------------------------------------------------------------
// Main v9 == round-0 kernel (16 rows/wave, no prefetch, VGPR=60) with ONE
// change: __launch_bounds__(256, 8) to force 8 waves/SIMD residency
// (32 waves/CU). Theory: every prior round ran at ~13 waves/CU (unified
// VGPR+AGPR accounting pushed the real footprint past 64); the read wall
// at ~2.8 TB/s is pure Little's-law concurrency shortage. TLP, not MLP,
// is how m13's copy reaches 6.3 TB/s.
// ---------------------------------------------------------------------------
__global__ __launch_bounds__(256, 8) void pb_main(
    const float* __restrict__ seg,
    const unsigned short* __restrict__ pnorm,    // [64][512] bf16
    const unsigned short* __restrict__ protosT,  // [512][64] bf16
    float* __restrict__ out_pat,                 // [N][512]
    float* __restrict__ out_w,                   // [N][64]
    float* __restrict__ out_log) {               // [N][64]

    __shared__ unsigned short wbuf_all[4 * 16 * 64];  // 2KB per wave

    const int wid  = (int)(threadIdx.x >> 6);
    const int lane = (int)(threadIdx.x & 63);
    const int g    = lane >> 4;    // quarter-wave
    const int r16  = lane & 15;
    const long n0  = ((long)blockIdx.x * 4 + wid) * 16;  // first row of tile

    // ---------------- logits matmul: K = 512, 4 proto col-tiles ----------------
    f32x4 acc[4] = {};
    float ss = 0.0f;
    const float* aptr = seg + (n0 + r16) * DIM + g * 8;
#pragma unroll 4
    for (int kt = 0; kt < 16; ++kt) {
        const f32x4 a0 = *reinterpret_cast<const f32x4*>(aptr + kt * 32);
        const f32x4 a1 = *reinterpret_cast<const f32x4*>(aptr + kt * 32 + 4);
        short8 af;
#pragma unroll
        for (int j = 0; j < 4; ++j) {
            ss += a0[j] * a0[j];
            ss += a1[j] * a1[j];
            af[j]     = (short)f2bf(a0[j]);
            af[j + 4] = (short)f2bf(a1[j]);
        }
#pragma unroll
        for (int c = 0; c < 4; ++c) {
            const short8 bf = *reinterpret_cast<const short8*>(
                pnorm + (c * 16 + r16) * DIM + g * 8 + kt * 32);
            acc[c] = __builtin_amdgcn_mfma_f32_16x16x32_bf16(af, bf, acc[c], 0, 0, 0);
        }
    }

    // per-row 1/|z| (lane covered row r16); redistribute to D-layout rows
    ss += __shfl_xor(ss, 16, 64);
    ss += __shfl_xor(ss, 32, 64);
    const float sc_own = TAU_INV / fmaxf(sqrtf(ss), 1e-12f);
    float sc[4];
#pragma unroll
    for (int q = 0; q < 4; ++q) sc[q] = __shfl(sc_own, g * 4 + q, 64);

    float lg[4][4];
#pragma unroll
    for (int c = 0; c < 4; ++c)
#pragma unroll
        for (int q = 0; q < 4; ++q) {
            lg[c][q] = acc[c][q] * sc[q];
            out_log[(n0 + g * 4 + q) * NPROTO + c * 16 + r16] = lg[c][q];
        }

    // ---------------- softmax over 64 protos per row ----------------
    float w[4][4];
#pragma unroll
    for (int q = 0; q < 4; ++q) {
        float mx = fmaxf(fmaxf(lg[0][q], lg[1][q]), fmaxf(lg[2][q], lg[3][q]));
#pragma unroll
        for (int msk = 1; msk < 16; msk <<= 1) mx = fmaxf(mx, __shfl_xor(mx, msk, 64));
        const float e0 = __expf(lg[0][q] - mx);
        const float e1 = __expf(lg[1][q] - mx);
        const float e2 = __expf(lg[2][q] - mx);
        const float e3 = __expf(lg[3][q] - mx);
        float sum = e0 + e1 + e2 + e3;
#pragma unroll
        for (int msk = 1; msk < 16; msk <<= 1) sum += __shfl_xor(sum, msk, 64);
        const float inv = 1.0f / sum;
        w[0][q] = e0 * inv; w[1][q] = e1 * inv; w[2][q] = e2 * inv; w[3][q] = e3 * inv;
    }

    // store w + LDS transpose (D-layout -> A-layout), XOR-swizzled vs 16-way conflict
    unsigned short* wb = wbuf_all + wid * (16 * 64);
#pragma unroll
    for (int c = 0; c < 4; ++c)
#pragma unroll
        for (int q = 0; q < 4; ++q) {
            out_w[(n0 + g * 4 + q) * NPROTO + c * 16 + r16] = w[c][q];
            const int row  = g * 4 + q;
            const int col  = c * 16 + r16;
            const int byte = (row * 128 + col * 2) ^ ((row & 7) << 4);
            *reinterpret_cast<unsigned short*>(reinterpret_cast<char*>(wb) + byte) =
                f2bf(w[c][q]);
        }

    __syncthreads();  // cheap; guarantees LDS writes visible

    short8 wa0, wa1;
    {
        const int row = r16;
        const int b0 = (row * 128 + g * 16)      ^ ((row & 7) << 4);
        const int b1 = (row * 128 + g * 16 + 64) ^ ((row & 7) << 4);
        wa0 = *reinterpret_cast<const short8*>(reinterpret_cast<char*>(wb) + b0);
        wa1 = *reinterpret_cast<const short8*>(reinterpret_cast<char*>(wb) + b1);
    }

    // ---------------- pattern = w · protos : K = 64, 32 col-tiles ----------------
#pragma unroll 2
    for (int cp = 0; cp < 32; ++cp) {
        const unsigned short* bp = protosT + (cp * 16 + r16) * NPROTO + g * 8;
        const short8 b0 = *reinterpret_cast<const short8*>(bp);
        const short8 b1 = *reinterpret_cast<const short8*>(bp + 32);
        f32x4 pacc = {};
        pacc = __builtin_amdgcn_mfma_f32_16x16x32_bf16(wa0, b0, pacc, 0, 0, 0);
        pacc = __builtin_amdgcn_mfma_f32_16x16x32_bf16(wa1, b1, pacc, 0, 0, 0);
#pragma unroll
        for (int q = 0; q < 4; ++q)
            out_pat[(n0 + g * 4 + q) * DIM + cp * 16 + r16] = pacc[q];
    }
}

extern "C" void kernel_launch(void* const* d_in, const int* in_sizes, int n_in,
                              void* d_out, int out_size, void* d_ws, size_t ws_size,
                              hipStream_t stream) {
    const float* seg    = (const float*)d_in[0];
    const float* protos = (const float*)d_in[1];
    const int N = in_sizes[0] / DIM;  // 131072

    float* out     = (float*)d_out;
    float* out_pat = out;
    float* out_w   = out_pat + (size_t)N * DIM;
    float* out_log = out_w + (size_t)N * NPROTO;

    unsigned short* pnorm   = (unsigned short*)d_ws;          // 64KB
    unsigned short* protosT = pnorm + NPROTO * DIM;           // 64KB

    pb_prep<<<NPROTO, 64, 0, stream>>>(protos, pnorm, protosT);
    pb_main<<<N / 64, 256, 0, stream>>>(seg, pnorm, protosT, out_pat, out_w, out_log);
}